// Round 1
// baseline (296.105 us; speedup 1.0000x reference)
//
#include <hip/hip_runtime.h>

// Problem constants (from reference)
#define QLEN 1024
#define KLEN 2048   // MLEN + QLEN
#define BSZ 4
#define NHEAD 8
#define DHEAD 16
#define DMODEL 128

static constexpr float INV2PI = 0.15915494309189535f;

// ---------------------------------------------------------------------------
// Projection: out[row][col] = (sum_e in[row][e] * W[e][col]) * R[col>>4]/(2pi)
// rows = token*BSZ + b. For the K projection, rows >= 4096 come from inB (=h).
// Block: 32 rows x 128 cols, 256 threads. Input rows staged transposed in LDS.
// ---------------------------------------------------------------------------
__global__ __launch_bounds__(256) void fa_proj_kernel(
    const float* __restrict__ inA, const float* __restrict__ inB,
    const float* __restrict__ W, const float* __restrict__ paramR,
    float* __restrict__ outp)
{
    __shared__ float inT[128 * 36];   // [e][row], stride 36 (16B-aligned, bank-spread)
    const int tid  = threadIdx.x;
    const int row0 = blockIdx.x * 32;

    for (int idx = tid; idx < 32 * 128; idx += 256) {
        int r = idx >> 7;
        int e = idx & 127;
        int grow = row0 + r;
        float v = (inB == nullptr || grow < 4096)
                ? inA[(size_t)grow * 128 + e]
                : inB[(size_t)(grow - 4096) * 128 + e];
        inT[e * 36 + r] = v;
    }
    __syncthreads();

    const int col  = tid & 127;
    const int half = tid >> 7;   // 0 or 1 -> rows [0..15] / [16..31]

    float acc[16];
#pragma unroll
    for (int j = 0; j < 16; ++j) acc[j] = 0.0f;

#pragma unroll 2
    for (int e = 0; e < 128; ++e) {
        float w = W[e * 128 + col];
        const float4* ap = reinterpret_cast<const float4*>(&inT[e * 36 + half * 16]);
        float4 a0 = ap[0], a1 = ap[1], a2 = ap[2], a3 = ap[3];
        float av[16];
        av[0]=a0.x; av[1]=a0.y; av[2]=a0.z; av[3]=a0.w;
        av[4]=a1.x; av[5]=a1.y; av[6]=a1.z; av[7]=a1.w;
        av[8]=a2.x; av[9]=a2.y; av[10]=a2.z; av[11]=a2.w;
        av[12]=a3.x; av[13]=a3.y; av[14]=a3.z; av[15]=a3.w;
#pragma unroll
        for (int j = 0; j < 16; ++j) acc[j] = fmaf(av[j], w, acc[j]);
    }

    const float sc = paramR[col >> 4] * INV2PI;
    const int orow = row0 + half * 16;
#pragma unroll
    for (int j = 0; j < 16; ++j)
        outp[(size_t)(orow + j) * 128 + col] = acc[j] * sc;
}

// ---------------------------------------------------------------------------
// Main: out[q][k][b][h] = | prod_d Rrev * sin(2pi*u_d) / u_d |,
//   u_d = Rq[q,b,h,d] - Rk[k,b,h,d]  (already scaled by R/(2pi))
// Guard (ref: |diff|<1e-6 -> R): |u| < |Rrev|*1e-6 -> s=1, u=1/(2pi).
// One rcp per quad of d: factor = Rrev^4 * (s0 s1 s2 s3) * rcp(u0 u1 u2 u3).
// Block: 4 q's (registers) x 256 k's (streamed). lane = (k_local, b*8+h)
// -> wave stores 256 B contiguous. Non-temporal stores keep Rk L2-resident.
// ---------------------------------------------------------------------------
__global__ __launch_bounds__(256) void fa_fourier_main(
    const float* __restrict__ Rq, const float* __restrict__ Rk,
    const float* __restrict__ paramR, float* __restrict__ out)
{
    const int tid = threadIdx.x;
    const int bh  = tid & 31;          // b*8 + h
    const int kl  = tid >> 5;          // 0..7
    const int q0  = blockIdx.x * 4;
    const int k0  = blockIdx.y * 256;

    const float R    = paramR[bh & 7];
    const float Rrev = R * INV2PI;
    const float r2   = Rrev * Rrev;
    const float C4   = r2 * r2;                 // Rrev^4 (even power, sign-safe)
    const float Tg   = fabsf(Rrev) * 1e-6f;     // guard threshold in u-units

    // q-state: 4 q's x 16 d in registers (all indices compile-time after unroll)
    float qv[4][16];
#pragma unroll
    for (int qq = 0; qq < 4; ++qq) {
        const float4* p = reinterpret_cast<const float4*>(
            Rq + ((size_t)(q0 + qq) * 32 + bh) * 16);
#pragma unroll
        for (int t = 0; t < 4; ++t) {
            float4 a = p[t];
            qv[qq][t*4+0] = a.x; qv[qq][t*4+1] = a.y;
            qv[qq][t*4+2] = a.z; qv[qq][t*4+3] = a.w;
        }
    }

    for (int i = 0; i < 32; ++i) {
        const int k = k0 + i * 8 + kl;
        float kv[16];
        const float4* pk = reinterpret_cast<const float4*>(
            Rk + ((size_t)k * 32 + bh) * 16);
#pragma unroll
        for (int t = 0; t < 4; ++t) {
            float4 a = pk[t];
            kv[t*4+0] = a.x; kv[t*4+1] = a.y;
            kv[t*4+2] = a.z; kv[t*4+3] = a.w;
        }

#pragma unroll
        for (int qq = 0; qq < 4; ++qq) {
            float p = 1.0f;
#pragma unroll
            for (int t = 0; t < 4; ++t) {
                float u0 = qv[qq][t*4+0] - kv[t*4+0];
                float u1 = qv[qq][t*4+1] - kv[t*4+1];
                float u2 = qv[qq][t*4+2] - kv[t*4+2];
                float u3 = qv[qq][t*4+3] - kv[t*4+3];
                float s0 = __builtin_amdgcn_sinf(u0);   // v_sin: sin(2*pi*u)
                float s1 = __builtin_amdgcn_sinf(u1);
                float s2 = __builtin_amdgcn_sinf(u2);
                float s3 = __builtin_amdgcn_sinf(u3);
                bool g0 = fabsf(u0) < Tg;
                bool g1 = fabsf(u1) < Tg;
                bool g2 = fabsf(u2) < Tg;
                bool g3 = fabsf(u3) < Tg;
                s0 = g0 ? 1.0f : s0;  u0 = g0 ? INV2PI : u0;   // guarded val == R
                s1 = g1 ? 1.0f : s1;  u1 = g1 ? INV2PI : u1;
                s2 = g2 ? 1.0f : s2;  u2 = g2 ? INV2PI : u2;
                s3 = g3 ? 1.0f : s3;  u3 = g3 ? INV2PI : u3;
                float uu = (u0 * u1) * (u2 * u3);
                float ss = ((s0 * s1) * (s2 * s3)) * C4;
                p = p * ss * __builtin_amdgcn_rcpf(uu);
            }
            __builtin_nontemporal_store(
                fabsf(p), &out[((size_t)(q0 + qq) * KLEN + k) * 32 + bh]);
        }
    }
}

extern "C" void kernel_launch(void* const* d_in, const int* in_sizes, int n_in,
                              void* d_out, int out_size, void* d_ws, size_t ws_size,
                              hipStream_t stream)
{
    const float* h    = (const float*)d_in[0];   // [1024,4,128]
    const float* mems = (const float*)d_in[1];   // [1024,4,128]
    const float* Wq   = (const float*)d_in[2];   // [128,128]
    const float* Wk   = (const float*)d_in[3];   // [128,128]
    const float* R    = (const float*)d_in[4];   // [8]
    float* out = (float*)d_out;                  // [1024,2048,4,8]

    float* Rq = (float*)d_ws;                    // 4096*128 floats (2 MB)
    float* Rk = Rq + 4096 * 128;                 // 8192*128 floats (4 MB)

    // Projections: q from h (4096 rows), k from concat(mems, h) (8192 rows)
    fa_proj_kernel<<<dim3(4096 / 32), 256, 0, stream>>>(h, nullptr, Wq, R, Rq);
    fa_proj_kernel<<<dim3(8192 / 32), 256, 0, stream>>>(mems, h, Wk, R, Rk);

    // Main scores kernel: grid = (1024/4 q-blocks, 2048/256 k-splits)
    fa_fourier_main<<<dim3(QLEN / 4, KLEN / 256), 256, 0, stream>>>(Rq, Rk, R, out);
}